// Round 8
// baseline (727.821 us; speedup 1.0000x reference)
//
#include <hip/hip_runtime.h>

#define B_   32
#define L_   512
#define S1_  513
#define LP_  16
#define NEG  (-1.0e9f)
#define NINF (-3.0e38f)
#define L2E  1.4426950408889634f
#define LN2f 0.6931471805599453f

typedef unsigned short ushort_t;
typedef unsigned int   uint_t;

#if defined(__has_builtin)
#if __has_builtin(__builtin_amdgcn_fdot2_f32_bf16)
#define HAS_DOT2 1
#endif
#endif

#ifdef HAS_DOT2
typedef __bf16 bf16x2_t __attribute__((ext_vector_type(2)));
#endif

__device__ __forceinline__ float bf2f(ushort_t u) {
  return __uint_as_float(((uint_t)u) << 16);
}
__device__ __forceinline__ ushort_t f2bf(float f) {
  uint_t u = __float_as_uint(f);
  uint_t r = (u + 0x7FFFu + ((u >> 16) & 1u)) >> 16;
  return (ushort_t)r;
}
__device__ __forceinline__ float dot2p(uint_t e, uint_t w, float c) {
#ifdef HAS_DOT2
  return __builtin_amdgcn_fdot2_f32_bf16(__builtin_bit_cast(bf16x2_t, e),
                                         __builtin_bit_cast(bf16x2_t, w), c, false);
#else
  return fmaf(__uint_as_float(e & 0xffff0000u), __uint_as_float(w & 0xffff0000u),
              fmaf(__uint_as_float(e << 16), __uint_as_float(w << 16), c));
#endif
}

// ---------------- setup kernels ----------------

// cumsum of log ss3 + zero the sync counters (block 0,0)
__global__ void k_cumsum(const float* __restrict__ ss3, float* __restrict__ cs,
                         int* __restrict__ sync_cnt) {
  int b = blockIdx.x, c = blockIdx.y;
  if (b == 0 && c == 0) {
    for (int i = threadIdx.x; i < 64 * LP_; i += 512) sync_cnt[i] = 0;
  }
  __shared__ float buf[L_];
  int t = threadIdx.x;
  buf[t] = logf(ss3[(b * 3 + c) * L_ + t]);
  __syncthreads();
  for (int d = 1; d < L_; d <<= 1) {
    float add = (t >= d) ? buf[t - d] : 0.0f;
    __syncthreads();
    buf[t] += add;
    __syncthreads();
  }
  float* out = cs + (b * 3 + c) * S1_;
  if (t == 0) out[0] = 0.0f;
  out[t + 1] = buf[t];
}

// Efo[(c*64+jo)*513 + k] : uint4 = rows 8jo..8jo+7 (bf16 of exp Q) at column k
// Ebo[(c*65+ko)*512 + j] : uint4 = cols 8ko..8ko+7 at row j (cols>=513 padded 0)
__global__ void k_prep(const float* __restrict__ Q, uint4* __restrict__ Efo,
                       uint4* __restrict__ Ebo) {
  __shared__ float tile[64][65];
  const int kt = blockIdx.x;       // 0..8
  const int jt = blockIdx.y;       // 0..7
  const int c  = blockIdx.z;
  const int x = threadIdx.x;       // 0..63
  const int y = threadIdx.y;       // 0..7
  const float* q = Q + (size_t)c * S1_ * S1_;

  for (int rr = y; rr < 64; rr += 8) {
    int row = jt * 64 + rr;
    int col = kt * 64 + x;
    float e = 0.0f;
    if (col < S1_) e = expf(q[row * S1_ + col]);
    tile[rr][x] = e;
  }
  __syncthreads();
  {
    int col = kt * 64 + x;
    if (col < S1_) {
      uint_t d0 = (uint_t)f2bf(tile[y * 8 + 0][x]) | ((uint_t)f2bf(tile[y * 8 + 1][x]) << 16);
      uint_t d1 = (uint_t)f2bf(tile[y * 8 + 2][x]) | ((uint_t)f2bf(tile[y * 8 + 3][x]) << 16);
      uint_t d2 = (uint_t)f2bf(tile[y * 8 + 4][x]) | ((uint_t)f2bf(tile[y * 8 + 5][x]) << 16);
      uint_t d3 = (uint_t)f2bf(tile[y * 8 + 6][x]) | ((uint_t)f2bf(tile[y * 8 + 7][x]) << 16);
      Efo[((size_t)c * 64 + jt * 8 + y) * 513 + col] = make_uint4(d0, d1, d2, d3);
    }
  }
  {
    int ko = kt * 8 + y;
    if (ko < 65) {
      uint_t d0 = (uint_t)f2bf(tile[x][y * 8 + 0]) | ((uint_t)f2bf(tile[x][y * 8 + 1]) << 16);
      uint_t d1 = (uint_t)f2bf(tile[x][y * 8 + 2]) | ((uint_t)f2bf(tile[x][y * 8 + 3]) << 16);
      uint_t d2 = (uint_t)f2bf(tile[x][y * 8 + 4]) | ((uint_t)f2bf(tile[x][y * 8 + 5]) << 16);
      uint_t d3 = (uint_t)f2bf(tile[x][y * 8 + 6]) | ((uint_t)f2bf(tile[x][y * 8 + 7]) << 16);
      Ebo[((size_t)c * 65 + ko) * 512 + jt * 64 + x] = make_uint4(d0, d1, d2, d3);
    }
  }
}

// ---------------- main scan kernel ----------------
// 256 blocks x 512 threads; 4 blocks (q=0..3) per (b,dir) group, same-XCD mapped.
// Waves 0,1 own output tiles {q, 7-q}; waves 2..7 consume the 7 full subtile units.
// Cross-block per step: wexp[512] bf16 + 8 tile maxes via device-scope handshake.
__global__ __launch_bounds__(512) void k_scan(
    const uint4* __restrict__ Efo, const uint4* __restrict__ Ebo,
    const float* __restrict__ cs, const int* __restrict__ pattern,
    const int* __restrict__ ls,
    float* __restrict__ a_buf, float* __restrict__ b_buf,
    ushort_t* __restrict__ wexp_g, float* __restrict__ tmax_g,
    int* __restrict__ sync_cnt) {
  const int bid  = blockIdx.x;
  const int xcd  = bid & 7;
  const int slot = bid >> 3;
  const int grp  = xcd * 8 + (slot >> 2);   // 0..63, 4 blocks each, same XCD
  const int q    = slot & 3;
  const int b    = grp >> 1;
  const int dir  = grp & 1;
  const int tid  = threadIdx.x;
  const int wv   = tid >> 6;                // 0..7
  const int lane = tid & 63;
  const bool owner = wv < 2;
  const int tw   = (wv == 0) ? q : (7 - q); // owner tile
  const int myk  = tw * 64 + lane;

  __shared__ float zl_loc[2][64];
  __shared__ float tmx_loc[12];
  __shared__ float psum[7][64];
  __shared__ __align__(16) uint_t wloc[256];
  __shared__ int pat[LP_];

  if (tid < LP_) pat[tid] = pattern[tid];
  const int myls = ls[b];
  const float* csb = cs + (size_t)b * 3 * S1_;
  float* obuf = dir ? b_buf : a_buf;

  float areg = NEG;
  if (owner) {
    const int initk = dir ? myls : 0;
    areg = (myk == initk) ? 0.0f : NEG;
    const int row0 = dir ? LP_ : 0;
    obuf[(b * (LP_ + 1) + row0) * S1_ + myk] = areg;
    if (q == 3 && tid == 0)
      obuf[(b * (LP_ + 1) + row0) * S1_ + 512] = (dir && myls == 512) ? 0.0f : NEG;
  }
  __syncthreads();

  // consume-wave unit ids (flat 0..6): wave wv>=2 handles unit wv-2 (+6 if wv==2)
  const int uidA = owner ? -1 : (wv - 2);
  const int uidB = (!owner && wv == 2) ? 6 : -1;

  for (int s = 0; s < LP_; ++s) {
    const int c   = pat[dir ? (LP_ - 1 - s) : s];
    const int par = s & 1;
    const uint4* Ecf = Efo + (size_t)c * 64 * 513;
    const uint4* Ecb = Ebo + (size_t)c * 65 * 512;
    ushort_t* wg = wexp_g + ((size_t)grp * 2 + par) * 512;
    float*    tg = tmax_g + ((size_t)grp * 2 + par) * 8;
    int*      cf = sync_cnt + grp * LP_ + s;
    const float cs512 = csb[c * S1_ + 512];
    const float z512  = dir ? (((s == 0 && myls == 512) ? 0.0f : NEG) + cs512) : NEG;

    // unit decode: flat i -> (out tile, subtile u)
    int tA = 0, uA = 0, tB = 0, uB = 0;
    if (!owner) {
      if (!dir) { if (uidA < q) { tA = q; uA = uidA; } else { tA = 7 - q; uA = uidA - q; } }
      else      { if (uidA < 7 - q) { tA = q; uA = q + 1 + uidA; } else { tA = 7 - q; uA = uidA + 1; } }
      if (uidB >= 0) {  // uidB == 6
        if (!dir) { tB = 7 - q; uB = 6 - q; }
        else      { tB = 7 - q; uB = 7; }
      }
    }

    // ---- prefetch E into VGPRs (addresses known pre-sync) ----
    uint4 eA[8], eB[8];
    uint4 e512c = make_uint4(0, 0, 0, 0);
    ushort_t e512b = 0;
    if (!owner) {
      const int str = dir ? 512 : 513;
      const uint4* baseA = (dir ? Ecb : Ecf) + (uA * 8) * str + tA * 64 + lane;
      #pragma unroll
      for (int jo = 0; jo < 8; ++jo) eA[jo] = baseA[jo * str];
      if (uidB >= 0) {
        const uint4* baseB = (dir ? Ecb : Ecf) + (uB * 8) * str + tB * 64 + lane;
        #pragma unroll
        for (int jo = 0; jo < 8; ++jo) eB[jo] = baseB[jo * str];
      }
    } else {
      const int str = dir ? 512 : 513;
      const uint4* baseD = (dir ? Ecb : Ecf) + (tw * 8) * str + tw * 64 + lane;
      #pragma unroll
      for (int jo = 0; jo < 8; ++jo) eA[jo] = baseD[jo * str];
      if (dir) e512b = ((const ushort_t*)(Ecb + 64 * 512 + myk))[0];
      if (!dir && q == 3 && wv == 0) e512c = Ecf[lane * 513 + 512];
    }

    // ---- phase A (owners): z, prefix max scan, publish wexp + tmax ----
    float z = 0.f, pfx = NINF, tmax = 0.f, mycs = 0.f;
    if (owner) {
      mycs = csb[c * S1_ + myk];
      z = areg + (dir ? mycs : -mycs);
      zl_loc[wv][lane] = z;
      pfx = z;
      if (!dir) {
        #pragma unroll
        for (int d = 1; d < 64; d <<= 1) {
          float o = __shfl_up(pfx, d);
          if (lane >= d) pfx = fmaxf(pfx, o);
        }
        tmax = __shfl(pfx, 63);
      } else {
        #pragma unroll
        for (int d = 1; d < 64; d <<= 1) {
          float o = __shfl_down(pfx, d);
          if (lane < 64 - d) pfx = fmaxf(pfx, o);
        }
        tmax = __shfl(pfx, 0);
      }
      wg[tw * 64 + lane] = f2bf(exp2f((z - tmax) * L2E));
      if (lane == 0) tg[tw] = tmax;
    }
    __syncthreads();                                   // #1: publishes + prefetch drained

    if (tid == 0) {
      __threadfence();                                 // release
      __hip_atomic_fetch_add(cf, 1, __ATOMIC_RELAXED, __HIP_MEMORY_SCOPE_AGENT);
    }
    if (lane == 0) {
      while (__hip_atomic_load(cf, __ATOMIC_RELAXED, __HIP_MEMORY_SCOPE_AGENT) < 4)
        __builtin_amdgcn_s_sleep(1);
    }
    __threadfence();                                   // acquire

    // ---- cooperative pull of group-wide wexp + tmax into LDS ----
    if (tid < 256) wloc[tid] = ((const uint_t*)wg)[tid];
    else if (tid < 256 + 8) tmx_loc[tid - 256] = tg[tid - 256];
    __syncthreads();                                   // #2

    float msh = 0.f, dacc = 0.f, a512val = NEG;
    if (!owner) {
      // full units: pure dot2, scale-free partials
      {
        float s0 = 0.f, s1 = 0.f, s2 = 0.f, s3 = 0.f;
        #pragma unroll
        for (int jo = 0; jo < 8; ++jo) {
          uint4 w4 = ((const uint4*)wloc)[uA * 8 + jo];
          s0 = dot2p(eA[jo].x, w4.x, s0);
          s1 = dot2p(eA[jo].y, w4.y, s1);
          s2 = dot2p(eA[jo].z, w4.z, s2);
          s3 = dot2p(eA[jo].w, w4.w, s3);
        }
        psum[uidA][lane] = (s0 + s1) + (s2 + s3);
      }
      if (uidB >= 0) {
        float s0 = 0.f, s1 = 0.f, s2 = 0.f, s3 = 0.f;
        #pragma unroll
        for (int jo = 0; jo < 8; ++jo) {
          uint4 w4 = ((const uint4*)wloc)[uB * 8 + jo];
          s0 = dot2p(eB[jo].x, w4.x, s0);
          s1 = dot2p(eB[jo].y, w4.y, s1);
          s2 = dot2p(eB[jo].z, w4.z, s2);
          s3 = dot2p(eB[jo].w, w4.w, s3);
        }
        psum[uidB][lane] = (s0 + s1) + (s2 + s3);
      }
    } else {
      // msh from own prefix + remote tile maxes (+z512 for bwd)
      float off = dir ? z512 : NINF;
      if (!dir) { for (int t2 = 0; t2 < tw; ++t2) off = fmaxf(off, tmx_loc[t2]); }
      else      { for (int t2 = tw + 1; t2 < 8; ++t2) off = fmaxf(off, tmx_loc[t2]); }
      float p1 = dir ? __shfl_down(pfx, 1) : __shfl_up(pfx, 1);
      bool edge = dir ? (lane == 63) : (lane == 0);
      msh = fmaxf(edge ? NINF : p1, off);
      // diagonal unit (exact per-element path)
      const float* zp = zl_loc[wv];
      #pragma unroll
      for (int jo = 0; jo < 8; ++jo) {
        uint_t ew0 = eA[jo].x, ew1 = eA[jo].y, ew2 = eA[jo].z, ew3 = eA[jo].w;
        #pragma unroll
        for (int r = 0; r < 8; ++r) {
          int jl = jo * 8 + r;
          bool live = dir ? (jl > lane) : (jl < lane);
          float a = live ? (zp[jl] - msh) : NEG;
          uint_t ew = (r < 2) ? ew0 : (r < 4) ? ew1 : (r < 6) ? ew2 : ew3;
          dacc += bf2f((ushort_t)(ew >> ((r & 1) * 16))) * exp2f(a * L2E);
        }
      }
      if (dir) dacc += bf2f(e512b) * exp2f((z512 - msh) * L2E);
      // fwd k=512 output column (q==3, wave 0)
      if (!dir && q == 3 && wv == 0) {
        float msh512 = tmx_loc[0];
        #pragma unroll
        for (int t2 = 1; t2 < 8; ++t2) msh512 = fmaxf(msh512, tmx_loc[t2]);
        uint4 w4 = ((const uint4*)wloc)[lane];
        float p = dot2p(e512c.x, w4.x, 0.f);
        p = dot2p(e512c.y, w4.y, p);
        p = dot2p(e512c.z, w4.z, p);
        p = dot2p(e512c.w, w4.w, p);
        p *= exp2f((tmx_loc[lane >> 3] - msh512) * L2E);
        #pragma unroll
        for (int o = 1; o < 64; o <<= 1) p += __shfl_xor(p, o);
        a512val = (p > 0.0f) ? (cs512 + msh512 + log2f(p) * LN2f) : NEG;
      }
    }
    __syncthreads();                                   // #3

    if (owner) {
      float acc = dacc;
      if (!dir) {
        if (wv == 0) { for (int i = 0; i < q; ++i)     acc += exp2f((tmx_loc[i] - msh) * L2E) * psum[i][lane]; }
        else         { for (int i = q; i < 7; ++i)     acc += exp2f((tmx_loc[i - q] - msh) * L2E) * psum[i][lane]; }
      } else {
        if (wv == 0) { for (int i = 0; i < 7 - q; ++i) acc += exp2f((tmx_loc[q + 1 + i] - msh) * L2E) * psum[i][lane]; }
        else         { for (int i = 7 - q; i < 7; ++i) acc += exp2f((tmx_loc[i + 1] - msh) * L2E) * psum[i][lane]; }
      }
      float ar = (acc > 0.0f) ? ((dir ? (msh - mycs) : (mycs + msh)) + log2f(acc) * LN2f) : NEG;
      areg = ar;
      const int row = dir ? (LP_ - 1 - s) : (s + 1);
      obuf[(b * (LP_ + 1) + row) * S1_ + myk] = ar;
      if (q == 3 && wv == 0 && lane == 0)
        obuf[(b * (LP_ + 1) + row) * S1_ + 512] = dir ? NEG : a512val;
    }
  }
}

// ---------------- epilogue ----------------
__global__ void k_out(const float* __restrict__ a_buf, const float* __restrict__ b_buf,
                      const int* __restrict__ ls, float* __restrict__ out) {
  const int TOT = B_ * (LP_ + 1) * S1_;
  int idx = blockIdx.x * 256 + threadIdx.x;
  if (idx >= TOT) return;
  int b = idx / ((LP_ + 1) * S1_);
  float M = a_buf[(b * (LP_ + 1) + LP_) * S1_ + ls[b]];
  out[idx] = a_buf[idx] + b_buf[idx] - M;
}

// ---------------- launcher ----------------
extern "C" void kernel_launch(void* const* d_in, const int* in_sizes, int n_in,
                              void* d_out, int out_size, void* d_ws, size_t ws_size,
                              hipStream_t stream) {
  const float* ss3     = (const float*)d_in[0];
  const float* Q       = (const float*)d_in[1];
  const int*   pattern = (const int*)d_in[2];
  const int*   ls      = (const int*)d_in[3];
  float* out = (float*)d_out;

  float* ws    = (float*)d_ws;
  float* cs    = ws;                                    // B*3*S1 floats
  float* a_buf = cs + B_ * 3 * S1_;                     // B*17*S1
  float* b_buf = a_buf + B_ * (LP_ + 1) * S1_;
  uint4* Efo = (uint4*)(b_buf + B_ * (LP_ + 1) * S1_);  // 3*64*513 uint4
  uint4* Ebo = Efo + 3 * 64 * 513;                      // 3*65*512 uint4
  ushort_t* wexp_g = (ushort_t*)(Ebo + 3 * 65 * 512);   // 64*2*512 ushort
  float* tmax_g = (float*)(wexp_g + 64 * 2 * 512);      // 64*2*8 f32
  int* sync_cnt = (int*)(tmax_g + 64 * 2 * 8);          // 64*16 int

  k_cumsum<<<dim3(B_, 3), 512, 0, stream>>>(ss3, cs, sync_cnt);
  k_prep  <<<dim3(9, 8, 3), dim3(64, 8), 0, stream>>>(Q, Efo, Ebo);
  k_scan  <<<256, 512, 0, stream>>>(Efo, Ebo, cs, pattern, ls, a_buf, b_buf,
                                    wexp_g, tmax_g, sync_cnt);

  const int TOT = B_ * (LP_ + 1) * S1_;
  k_out<<<(TOT + 255) / 256, 256, 0, stream>>>(a_buf, b_buf, ls, out);
}

// Round 9
// 232.144 us; speedup vs baseline: 3.1352x; 3.1352x over previous
//
#include <hip/hip_runtime.h>

#define B_   32
#define L_   512
#define S1_  513
#define LP_  16
#define NEG  (-1.0e9f)
#define NINF (-3.0e38f)
#define L2E  1.4426950408889634f
#define LN2f 0.6931471805599453f

typedef unsigned short ushort_t;
typedef unsigned int   uint_t;

#if defined(__has_builtin)
#if __has_builtin(__builtin_amdgcn_fdot2_f32_bf16)
#define HAS_DOT2 1
#endif
#endif

#ifdef HAS_DOT2
typedef __bf16 bf16x2_t __attribute__((ext_vector_type(2)));
#endif

__device__ __forceinline__ float bf2f(ushort_t u) {
  return __uint_as_float(((uint_t)u) << 16);
}
__device__ __forceinline__ ushort_t f2bf(float f) {
  uint_t u = __float_as_uint(f);
  uint_t r = (u + 0x7FFFu + ((u >> 16) & 1u)) >> 16;
  return (ushort_t)r;
}
__device__ __forceinline__ float dot2p(uint_t e, uint_t w, float c) {
#ifdef HAS_DOT2
  return __builtin_amdgcn_fdot2_f32_bf16(__builtin_bit_cast(bf16x2_t, e),
                                         __builtin_bit_cast(bf16x2_t, w), c, false);
#else
  return fmaf(__uint_as_float(e & 0xffff0000u), __uint_as_float(w & 0xffff0000u),
              fmaf(__uint_as_float(e << 16), __uint_as_float(w << 16), c));
#endif
}

// raw barrier: flush own LDS ops, sync. vmcnt (register prefetches) stays in flight.
__device__ __forceinline__ void sync_lgkm() {
  asm volatile("s_waitcnt lgkmcnt(0)" ::: "memory");
  __builtin_amdgcn_s_barrier();
  asm volatile("" ::: "memory");
}

struct HalfT { uint4 e0, e1, e2, e3; };

__device__ __forceinline__ void loadh(HalfT& hb, const uint4* Eb, int t, int h, int str) {
  const uint4* p = Eb + (t * 8 + h * 4) * str;
  hb.e0 = p[0];
  hb.e1 = p[str];
  hb.e2 = p[2 * str];
  hb.e3 = p[3 * str];
}

__device__ __forceinline__ void dotq(const HalfT& hb, const uint4* wq, int t, int h,
                                     float& s0, float& s1, float& s2, float& s3) {
  const uint4* wv = wq + t * 8 + h * 4;
  uint4 w;
  w = wv[0]; s0 = dot2p(hb.e0.x, w.x, s0); s1 = dot2p(hb.e0.y, w.y, s1);
             s2 = dot2p(hb.e0.z, w.z, s2); s3 = dot2p(hb.e0.w, w.w, s3);
  w = wv[1]; s0 = dot2p(hb.e1.x, w.x, s0); s1 = dot2p(hb.e1.y, w.y, s1);
             s2 = dot2p(hb.e1.z, w.z, s2); s3 = dot2p(hb.e1.w, w.w, s3);
  w = wv[2]; s0 = dot2p(hb.e2.x, w.x, s0); s1 = dot2p(hb.e2.y, w.y, s1);
             s2 = dot2p(hb.e2.z, w.z, s2); s3 = dot2p(hb.e2.w, w.w, s3);
  w = wv[3]; s0 = dot2p(hb.e3.x, w.x, s0); s1 = dot2p(hb.e3.y, w.y, s1);
             s2 = dot2p(hb.e3.z, w.z, s2); s3 = dot2p(hb.e3.w, w.w, s3);
}

// diagonal half: 32 j's (jl = h*32 + 0..31), exact per-element path
__device__ __forceinline__ float diagh(const HalfT& hb, const float* zp, float msh,
                                       int lane, int dir, int h) {
  float d = 0.f;
  const int jb = h * 32;
#define DIAG2(u, jl) { \
    bool l0 = dir ? ((jl) > lane) : ((jl) < lane); \
    bool l1 = dir ? ((jl) + 1 > lane) : ((jl) + 1 < lane); \
    d += bf2f((ushort_t)(u)) * exp2f((l0 ? (zp[(jl)] - msh) : NEG) * L2E); \
    d += bf2f((ushort_t)((u) >> 16)) * exp2f((l1 ? (zp[(jl) + 1] - msh) : NEG) * L2E); }
  DIAG2(hb.e0.x, jb + 0);  DIAG2(hb.e0.y, jb + 2);  DIAG2(hb.e0.z, jb + 4);  DIAG2(hb.e0.w, jb + 6);
  DIAG2(hb.e1.x, jb + 8);  DIAG2(hb.e1.y, jb + 10); DIAG2(hb.e1.z, jb + 12); DIAG2(hb.e1.w, jb + 14);
  DIAG2(hb.e2.x, jb + 16); DIAG2(hb.e2.y, jb + 18); DIAG2(hb.e2.z, jb + 20); DIAG2(hb.e2.w, jb + 22);
  DIAG2(hb.e3.x, jb + 24); DIAG2(hb.e3.y, jb + 26); DIAG2(hb.e3.z, jb + 28); DIAG2(hb.e3.w, jb + 30);
#undef DIAG2
  return d;
}

// ---------------- setup kernels ----------------

__global__ void k_cumsum(const float* __restrict__ ss3, float* __restrict__ cs) {
  int b = blockIdx.x, c = blockIdx.y;
  __shared__ float buf[L_];
  int t = threadIdx.x;
  buf[t] = logf(ss3[(b * 3 + c) * L_ + t]);
  __syncthreads();
  for (int d = 1; d < L_; d <<= 1) {
    float add = (t >= d) ? buf[t - d] : 0.0f;
    __syncthreads();
    buf[t] += add;
    __syncthreads();
  }
  float* out = cs + (b * 3 + c) * S1_;
  if (t == 0) out[0] = 0.0f;
  out[t + 1] = buf[t];
}

// Efo[(c*64+jo)*513 + k] : uint4 = rows 8jo..8jo+7 (bf16 of exp Q) at column k
// Ebo[(c*65+ko)*512 + j] : uint4 = cols 8ko..8ko+7 at row j (cols>=513 padded 0)
__global__ void k_prep(const float* __restrict__ Q, uint4* __restrict__ Efo,
                       uint4* __restrict__ Ebo) {
  __shared__ float tile[64][65];
  const int kt = blockIdx.x;       // 0..8
  const int jt = blockIdx.y;       // 0..7
  const int c  = blockIdx.z;
  const int x = threadIdx.x;       // 0..63
  const int y = threadIdx.y;       // 0..7
  const float* q = Q + (size_t)c * S1_ * S1_;

  for (int rr = y; rr < 64; rr += 8) {
    int row = jt * 64 + rr;
    int col = kt * 64 + x;
    float e = 0.0f;
    if (col < S1_) e = expf(q[row * S1_ + col]);
    tile[rr][x] = e;
  }
  __syncthreads();
  {
    int col = kt * 64 + x;
    if (col < S1_) {
      uint_t d0 = (uint_t)f2bf(tile[y * 8 + 0][x]) | ((uint_t)f2bf(tile[y * 8 + 1][x]) << 16);
      uint_t d1 = (uint_t)f2bf(tile[y * 8 + 2][x]) | ((uint_t)f2bf(tile[y * 8 + 3][x]) << 16);
      uint_t d2 = (uint_t)f2bf(tile[y * 8 + 4][x]) | ((uint_t)f2bf(tile[y * 8 + 5][x]) << 16);
      uint_t d3 = (uint_t)f2bf(tile[y * 8 + 6][x]) | ((uint_t)f2bf(tile[y * 8 + 7][x]) << 16);
      Efo[((size_t)c * 64 + jt * 8 + y) * 513 + col] = make_uint4(d0, d1, d2, d3);
    }
  }
  {
    int ko = kt * 8 + y;
    if (ko < 65) {
      uint_t d0 = (uint_t)f2bf(tile[x][y * 8 + 0]) | ((uint_t)f2bf(tile[x][y * 8 + 1]) << 16);
      uint_t d1 = (uint_t)f2bf(tile[x][y * 8 + 2]) | ((uint_t)f2bf(tile[x][y * 8 + 3]) << 16);
      uint_t d2 = (uint_t)f2bf(tile[x][y * 8 + 4]) | ((uint_t)f2bf(tile[x][y * 8 + 5]) << 16);
      uint_t d3 = (uint_t)f2bf(tile[x][y * 8 + 6]) | ((uint_t)f2bf(tile[x][y * 8 + 7]) << 16);
      Ebo[((size_t)c * 65 + ko) * 512 + jt * 64 + x] = make_uint4(d0, d1, d2, d3);
    }
  }
}

// ---------------- main scan kernel ----------------
// 64 blocks x 1024 threads: blockIdx.x = b*2 + dir (R6 topology, self-contained).
// Phase 4: register-staged ping-pong half-units, no inline asm in loop.
__global__ __launch_bounds__(1024) void k_scan(
    const uint4* __restrict__ Efo, const uint4* __restrict__ Ebo,
    const float* __restrict__ cs, const int* __restrict__ pattern,
    const int* __restrict__ ls,
    float* __restrict__ a_buf, float* __restrict__ b_buf) {
  const int b   = blockIdx.x >> 1;
  const int dir = blockIdx.x & 1;
  const int tid = threadIdx.x;
  const int wf  = tid >> 6;                  // 0..15
  const bool pri = wf < 8;
  const int lane = tid & 63;
  const int w8   = wf & 7;
  const int tile = (w8 < 4) ? w8 : (11 - w8);
  const int myk  = tile * 64 + lane;

  __shared__ __align__(16) ushort_t wpk[512];
  __shared__ float cs3[3 * S1_];
  __shared__ float zl[S1_];
  __shared__ float mshl[512];
  __shared__ float psum[512];
  __shared__ float tmaxs[2][9];              // parity double-buffered; [8] = z512 (bwd)
  __shared__ float red[8];
  __shared__ int   pat[LP_];

  for (int i = tid; i < 3 * S1_; i += 1024) cs3[i] = cs[b * 3 * S1_ + i];
  if (tid < LP_) pat[tid] = pattern[tid];
  const int myls = ls[b];

  // wave-uniform subtile schedule (unit = 64x64 block; diag handled by sec)
  int nsub;
  if (!dir) nsub = pri ? ((tile + 1) >> 1) : ((tile >> 1) + 1);
  else      nsub = pri ? ((8 - tile) >> 1) : (((7 - tile) >> 1) + 1);
  const int nh = nsub * 2;

  float* obuf = dir ? b_buf : a_buf;
  float areg = NEG, areg512 = NEG;
  if (pri) {
    const int initk = dir ? myls : 0;
    areg    = (myk == initk) ? 0.0f : NEG;
    areg512 = (dir && myls == 512) ? 0.0f : NEG;
    const int row0 = dir ? LP_ : 0;
    float* orow = obuf + (b * (LP_ + 1) + row0) * S1_;
    orow[myk] = areg;
    if (tid == 0) orow[512] = areg512;
  }
  __syncthreads();

  for (int s = 0; s < LP_; ++s) {
    const int c = pat[dir ? (LP_ - 1 - s) : s];
    const float* csr = cs3 + c * S1_;
    const uint4* Ecf = Efo + (size_t)c * 64 * 513;
    const uint4* Ecb = Ebo + (size_t)c * 65 * 512;
    float* tmx = tmaxs[s & 1];
    const uint4* wq = (const uint4*)wpk;
    const int str = dir ? 512 : 513;
    const uint4* Eb = (dir ? Ecb : Ecf) + tile * 64 + lane;

    auto UNIT = [&](int si) -> int {
      if (!dir) return pri ? (si << 1) : ((si < (tile >> 1)) ? ((si << 1) + 1) : tile);
      return pri ? (tile + 1 + (si << 1)) : (si == 0 ? tile : tile + (si << 1));
    };
    auto ISDIAG = [&](int si) -> bool {
      return !pri && (dir ? (si == 0) : (si == nsub - 1));
    };

    // ---- prologue prefetch: first half-unit into registers (crosses barriers) ----
    HalfT bufA, bufB;
    if (nh) loadh(bufA, Eb, UNIT(0), 0, str);
    ushort_t e512b = 0;
    if (dir && !pri) e512b = ((const ushort_t*)(Ecb + 64 * 512 + myk))[0];

    // ---- phase A (owners): z, per-tile scan, publish tmax ----
    float z = 0.f, pfx = NINF, tmax = 0.f;
    if (pri) {
      const float mycs = csr[myk];
      z = areg + (dir ? mycs : -mycs);
      zl[myk] = z;
      pfx = z;
      if (!dir) {
        #pragma unroll
        for (int d = 1; d < 64; d <<= 1) {
          float o = __shfl_up(pfx, d);
          if (lane >= d) pfx = fmaxf(pfx, o);
        }
        tmax = __shfl(pfx, 63);
        if (lane == 63) tmx[tile] = pfx;
      } else {
        #pragma unroll
        for (int d = 1; d < 64; d <<= 1) {
          float o = __shfl_down(pfx, d);
          if (lane < 64 - d) pfx = fmaxf(pfx, o);
        }
        tmax = __shfl(pfx, 0);
        if (lane == 0) tmx[tile] = pfx;
        if (tid == 0) tmx[8] = areg512 + csr[512];
      }
    }
    sync_lgkm();                                   // barrier A

    float msh = 0.f;
    if (pri) {
      // ---- phase B: per-column shift msh; publish packed-bf16 w ----
      if (!dir) {
        float off = NINF;
        for (int t2 = 0; t2 < tile; ++t2) off = fmaxf(off, tmx[t2]);
        float p1 = __shfl_up(pfx, 1);
        msh = fmaxf((lane == 0) ? NINF : p1, off);
      } else {
        float off = tmx[8];
        for (int t2 = tile + 1; t2 < 8; ++t2) off = fmaxf(off, tmx[t2]);
        float p1 = __shfl_down(pfx, 1);
        msh = fmaxf((lane == 63) ? NINF : p1, off);
      }
      mshl[myk] = msh;
      wpk[myk] = f2bf(exp2f((z - tmax) * L2E));
    }
    sync_lgkm();                                   // barrier B
    if (!pri) msh = mshl[myk];

    // ---- phase 4: software-pipelined half-unit consume ----
    float acc = 0.f, s0 = 0.f, s1 = 0.f, s2 = 0.f, s3 = 0.f;
    const float* zp = zl + tile * 64;

#define CONSH(BUF, hi_) { \
      const int si_ = (hi_) >> 1; const int h_ = (hi_) & 1; const int t_ = UNIT(si_); \
      if (ISDIAG(si_)) { \
        acc += diagh(BUF, zp, msh, lane, dir, h_); \
      } else { \
        dotq(BUF, wq, t_, h_, s0, s1, s2, s3); \
        if (h_ == 1) { \
          acc += exp2f((tmx[t_] - msh) * L2E) * ((s0 + s1) + (s2 + s3)); \
          s0 = s1 = s2 = s3 = 0.f; \
        } \
      } }

    for (int hi = 0; hi < nh; hi += 2) {
      if (hi + 1 < nh) loadh(bufB, Eb, UNIT((hi + 1) >> 1), (hi + 1) & 1, str);
      CONSH(bufA, hi);
      if (hi + 1 < nh) {
        if (hi + 2 < nh) loadh(bufA, Eb, UNIT((hi + 2) >> 1), (hi + 2) & 1, str);
        CONSH(bufB, hi + 1);
      }
    }
#undef CONSH

    // ---- post-pipeline extras ----
    float msh512 = NINF;
    if (!dir) {
      if (pri) {
        msh512 = tmx[0];
        #pragma unroll
        for (int t2 = 1; t2 < 8; ++t2) msh512 = fmaxf(msh512, tmx[t2]);
        float e512 = bf2f(((const ushort_t*)(Ecf + (tid >> 3) * 513 + 512))[tid & 7]);
        float p = e512 * bf2f(wpk[tid]) * exp2f((tmx[tid >> 6] - msh512) * L2E);
        #pragma unroll
        for (int o = 1; o < 64; o <<= 1) p += __shfl_xor(p, o);
        if (lane == 0) red[w8] = p;
      } else {
        psum[myk] = acc;
      }
    } else {
      if (!pri) {
        acc += bf2f(e512b) * exp2f((tmx[8] - msh) * L2E);   // k = 512 term
        psum[myk] = acc;
      }
    }
    sync_lgkm();                                   // barrier C

    if (pri) {
      acc += psum[myk];
      if (!dir) {
        float ar = (acc > 0.0f) ? (csr[myk] + msh + log2f(acc) * LN2f) : NEG;
        areg = ar;
        float* orow = obuf + (b * (LP_ + 1) + (s + 1)) * S1_;
        orow[myk] = ar;
        if (tid == 0) {
          float t2s = ((red[0] + red[1]) + (red[2] + red[3])) +
                      ((red[4] + red[5]) + (red[6] + red[7]));
          areg512 = (t2s > 0.0f) ? (csr[512] + msh512 + log2f(t2s) * LN2f) : NEG;
          orow[512] = areg512;
        }
      } else {
        float ar = (acc > 0.0f) ? (msh - csr[myk] + log2f(acc) * LN2f) : NEG;
        areg = ar;
        float* orow = obuf + (b * (LP_ + 1) + (LP_ - 1 - s)) * S1_;
        orow[myk] = ar;
        if (tid == 0) { areg512 = NEG; orow[512] = NEG; }
      }
    }
  }
}

// ---------------- epilogue ----------------
__global__ void k_out(const float* __restrict__ a_buf, const float* __restrict__ b_buf,
                      const int* __restrict__ ls, float* __restrict__ out) {
  const int TOT = B_ * (LP_ + 1) * S1_;
  int idx = blockIdx.x * 256 + threadIdx.x;
  if (idx >= TOT) return;
  int b = idx / ((LP_ + 1) * S1_);
  float M = a_buf[(b * (LP_ + 1) + LP_) * S1_ + ls[b]];
  out[idx] = a_buf[idx] + b_buf[idx] - M;
}

// ---------------- launcher ----------------
extern "C" void kernel_launch(void* const* d_in, const int* in_sizes, int n_in,
                              void* d_out, int out_size, void* d_ws, size_t ws_size,
                              hipStream_t stream) {
  const float* ss3     = (const float*)d_in[0];
  const float* Q       = (const float*)d_in[1];
  const int*   pattern = (const int*)d_in[2];
  const int*   ls      = (const int*)d_in[3];
  float* out = (float*)d_out;

  float* ws    = (float*)d_ws;
  float* cs    = ws;                                    // B*3*S1 floats
  float* a_buf = cs + B_ * 3 * S1_;                     // B*17*S1
  float* b_buf = a_buf + B_ * (LP_ + 1) * S1_;
  uint4* Efo = (uint4*)(b_buf + B_ * (LP_ + 1) * S1_);  // 3*64*513 uint4
  uint4* Ebo = Efo + 3 * 64 * 513;                      // 3*65*512 uint4

  k_cumsum<<<dim3(B_, 3), 512, 0, stream>>>(ss3, cs);
  k_prep  <<<dim3(9, 8, 3), dim3(64, 8), 0, stream>>>(Q, Efo, Ebo);
  k_scan  <<<2 * B_, 1024, 0, stream>>>(Efo, Ebo, cs, pattern, ls, a_buf, b_buf);

  const int TOT = B_ * (LP_ + 1) * S1_;
  k_out<<<(TOT + 255) / 256, 256, 0, stream>>>(a_buf, b_buf, ls, out);
}

// Round 10
// 169.082 us; speedup vs baseline: 4.3045x; 1.3730x over previous
//
#include <hip/hip_runtime.h>

#define B_   32
#define L_   512
#define S1_  513
#define LP_  16
#define NEG  (-1.0e9f)
#define NINF (-3.0e38f)
#define L2E  1.4426950408889634f
#define LN2f 0.6931471805599453f

typedef unsigned short ushort_t;
typedef unsigned int   uint_t;

#if defined(__has_builtin)
#if __has_builtin(__builtin_amdgcn_fdot2_f32_bf16)
#define HAS_DOT2 1
#endif
#endif

#ifdef HAS_DOT2
typedef __bf16 bf16x2_t __attribute__((ext_vector_type(2)));
#endif

__device__ __forceinline__ float bf2f(ushort_t u) {
  return __uint_as_float(((uint_t)u) << 16);
}
__device__ __forceinline__ ushort_t f2bf(float f) {
  uint_t u = __float_as_uint(f);
  uint_t r = (u + 0x7FFFu + ((u >> 16) & 1u)) >> 16;
  return (ushort_t)r;
}
__device__ __forceinline__ float dot2p(uint_t e, uint_t w, float c) {
#ifdef HAS_DOT2
  return __builtin_amdgcn_fdot2_f32_bf16(__builtin_bit_cast(bf16x2_t, e),
                                         __builtin_bit_cast(bf16x2_t, w), c, false);
#else
  return fmaf(__uint_as_float(e & 0xffff0000u), __uint_as_float(w & 0xffff0000u),
              fmaf(__uint_as_float(e << 16), __uint_as_float(w << 16), c));
#endif
}

// raw barrier: flush own LDS ops, sync. vmcnt (register prefetches) stays in flight.
__device__ __forceinline__ void sync_lgkm() {
  asm volatile("s_waitcnt lgkmcnt(0)" ::: "memory");
  __builtin_amdgcn_s_barrier();
  asm volatile("" ::: "memory");
}

struct HalfT { uint4 e0, e1, e2, e3; };

__device__ __forceinline__ void loadh(HalfT& hb, const uint4* Eb, int octbase, int str) {
  const uint4* p = Eb + octbase * str;
  hb.e0 = p[0];
  hb.e1 = p[str];
  hb.e2 = p[2 * str];
  hb.e3 = p[3 * str];
}

__device__ __forceinline__ void dotq(const HalfT& hb, const uint4* wq, int ob,
                                     float& s0, float& s1, float& s2, float& s3) {
  uint4 w;
  w = wq[ob + 0]; s0 = dot2p(hb.e0.x, w.x, s0); s1 = dot2p(hb.e0.y, w.y, s1);
                  s2 = dot2p(hb.e0.z, w.z, s2); s3 = dot2p(hb.e0.w, w.w, s3);
  w = wq[ob + 1]; s0 = dot2p(hb.e1.x, w.x, s0); s1 = dot2p(hb.e1.y, w.y, s1);
                  s2 = dot2p(hb.e1.z, w.z, s2); s3 = dot2p(hb.e1.w, w.w, s3);
  w = wq[ob + 2]; s0 = dot2p(hb.e2.x, w.x, s0); s1 = dot2p(hb.e2.y, w.y, s1);
                  s2 = dot2p(hb.e2.z, w.z, s2); s3 = dot2p(hb.e2.w, w.w, s3);
  w = wq[ob + 3]; s0 = dot2p(hb.e3.x, w.x, s0); s1 = dot2p(hb.e3.y, w.y, s1);
                  s2 = dot2p(hb.e3.z, w.z, s2); s3 = dot2p(hb.e3.w, w.w, s3);
}

// diag full-oct pass: octs jo = 4h..4h+3 (local), scale exp2(omx-msh), oct-normalized w2
__device__ __forceinline__ float diag_octs(const HalfT& hb, const float* omx8,
                                           const uint4* wq2t, float msh,
                                           int lo, int dir, int h) {
  float a = 0.f;
#define DOCT(E4, Q) { \
    const int jo = 4 * h + (Q); \
    bool valid = dir ? (jo > lo) : (jo < lo); \
    float sarg = valid ? (omx8[jo] - msh) : NEG; \
    uint4 w4 = wq2t[jo]; \
    float t = dot2p((E4).x, w4.x, 0.f); t = dot2p((E4).y, w4.y, t); \
    t = dot2p((E4).z, w4.z, t); t = dot2p((E4).w, w4.w, t); \
    a += exp2f(sarg * L2E) * t; }
  DOCT(hb.e0, 0) DOCT(hb.e1, 1) DOCT(hb.e2, 2) DOCT(hb.e3, 3)
#undef DOCT
  return a;
}

// ---------------- setup kernels ----------------

__global__ void k_cumsum(const float* __restrict__ ss3, float* __restrict__ cs) {
  int b = blockIdx.x, c = blockIdx.y;
  __shared__ float buf[L_];
  int t = threadIdx.x;
  buf[t] = logf(ss3[(b * 3 + c) * L_ + t]);
  __syncthreads();
  for (int d = 1; d < L_; d <<= 1) {
    float add = (t >= d) ? buf[t - d] : 0.0f;
    __syncthreads();
    buf[t] += add;
    __syncthreads();
  }
  float* out = cs + (b * 3 + c) * S1_;
  if (t == 0) out[0] = 0.0f;
  out[t + 1] = buf[t];
}

// Efo[(c*64+jo)*513 + k] : uint4 = rows 8jo..8jo+7 (bf16 of exp Q) at column k
// Ebo[(c*65+ko)*512 + j] : uint4 = cols 8ko..8ko+7 at row j (cols>=513 padded 0)
__global__ void k_prep(const float* __restrict__ Q, uint4* __restrict__ Efo,
                       uint4* __restrict__ Ebo) {
  __shared__ float tile[64][65];
  const int kt = blockIdx.x;       // 0..8
  const int jt = blockIdx.y;       // 0..7
  const int c  = blockIdx.z;
  const int x = threadIdx.x;       // 0..63
  const int y = threadIdx.y;       // 0..7
  const float* q = Q + (size_t)c * S1_ * S1_;

  for (int rr = y; rr < 64; rr += 8) {
    int row = jt * 64 + rr;
    int col = kt * 64 + x;
    float e = 0.0f;
    if (col < S1_) e = expf(q[row * S1_ + col]);
    tile[rr][x] = e;
  }
  __syncthreads();
  {
    int col = kt * 64 + x;
    if (col < S1_) {
      uint_t d0 = (uint_t)f2bf(tile[y * 8 + 0][x]) | ((uint_t)f2bf(tile[y * 8 + 1][x]) << 16);
      uint_t d1 = (uint_t)f2bf(tile[y * 8 + 2][x]) | ((uint_t)f2bf(tile[y * 8 + 3][x]) << 16);
      uint_t d2 = (uint_t)f2bf(tile[y * 8 + 4][x]) | ((uint_t)f2bf(tile[y * 8 + 5][x]) << 16);
      uint_t d3 = (uint_t)f2bf(tile[y * 8 + 6][x]) | ((uint_t)f2bf(tile[y * 8 + 7][x]) << 16);
      Efo[((size_t)c * 64 + jt * 8 + y) * 513 + col] = make_uint4(d0, d1, d2, d3);
    }
  }
  {
    int ko = kt * 8 + y;
    if (ko < 65) {
      uint_t d0 = (uint_t)f2bf(tile[x][y * 8 + 0]) | ((uint_t)f2bf(tile[x][y * 8 + 1]) << 16);
      uint_t d1 = (uint_t)f2bf(tile[x][y * 8 + 2]) | ((uint_t)f2bf(tile[x][y * 8 + 3]) << 16);
      uint_t d2 = (uint_t)f2bf(tile[x][y * 8 + 4]) | ((uint_t)f2bf(tile[x][y * 8 + 5]) << 16);
      uint_t d3 = (uint_t)f2bf(tile[x][y * 8 + 6]) | ((uint_t)f2bf(tile[x][y * 8 + 7]) << 16);
      Ebo[((size_t)c * 65 + ko) * 512 + jt * 64 + x] = make_uint4(d0, d1, d2, d3);
    }
  }
}

// ---------------- main scan kernel ----------------
// 64 blocks x 1024 threads: blockIdx.x = b*2 + dir. Waves 0-7 primary (own one
// output tile each: publish + even units + epilogue), waves 8-15 secondary
// (odd units + diag via oct-scales + partial + k512/e512). 2 barriers/step.
__global__ __launch_bounds__(1024, 4) void k_scan(
    const uint4* __restrict__ Efo, const uint4* __restrict__ Ebo,
    const float* __restrict__ cs, const int* __restrict__ pattern,
    const int* __restrict__ ls,
    float* __restrict__ a_buf, float* __restrict__ b_buf) {
  const int b   = blockIdx.x >> 1;
  const int dir = blockIdx.x & 1;
  const int tid = threadIdx.x;
  const int wf  = tid >> 6;
  const bool pri = wf < 8;
  const int lane = tid & 63;
  const int w8   = wf & 7;
  const int tile = (w8 < 4) ? w8 : (11 - w8);
  const int myk  = tile * 64 + lane;
  const int lo   = lane >> 3;

  __shared__ __align__(16) ushort_t wpk[2][512];   // tile-normalized weights (parity)
  __shared__ __align__(16) ushort_t wpk2[512];     // oct-normalized weights
  __shared__ float zl[512];
  __shared__ float omxl[64];                       // per-oct z max
  __shared__ float psum[512];
  __shared__ float tmx[2][12];                     // per-tile max (parity); [8]=z512 bwd
  __shared__ int   pat[LP_];

  if (tid < LP_) pat[tid] = pattern[tid];
  const int myls = ls[b];
  const float* csb = cs + (size_t)b * 3 * S1_;
  const float cs0 = csb[myk], cs1 = csb[S1_ + myk], cs2 = csb[2 * S1_ + myk];
  const float dd0 = csb[512], dd1 = csb[S1_ + 512], dd2 = csb[2 * S1_ + 512];
  float* obuf = dir ? b_buf : a_buf;

  float areg = NEG;
  if (pri) {
    const int initk = dir ? myls : 0;
    areg = (myk == initk) ? 0.f : NEG;
    float* orow = obuf + (b * (LP_ + 1) + (dir ? LP_ : 0)) * S1_;
    orow[myk] = areg;
    if (tid == 0) orow[512] = (dir && myls == 512) ? 0.f : NEG;
  }
  __syncthreads();

  for (int s = 0; s < LP_; ++s) {
    const int c = pat[dir ? LP_ - 1 - s : s];
    const int par = s & 1;
    const uint4* Ec = dir ? (Ebo + (size_t)c * 65 * 512) : (Efo + (size_t)c * 64 * 513);
    const int str = dir ? 512 : 513;
    const uint4* Eb = Ec + myk;
    const float mycs    = (c == 0) ? cs0 : ((c == 1) ? cs1 : cs2);
    const float mycs512 = (c == 0) ? dd0 : ((c == 1) ? dd1 : dd2);
    const uint4* wq   = (const uint4*)wpk[par];
    const uint4* wq2t = ((const uint4*)wpk2) + tile * 8;
    const float* omx8 = omxl + tile * 8;
    float* tmxp = tmx[par];

    // unit schedule: pri = even-indexed full units, sec = odd + diag
    int u0, nu;
    if (!dir) { if (pri) { u0 = 0;        nu = (tile + 1) >> 1; }
                else     { u0 = 1;        nu = tile >> 1; } }
    else      { if (pri) { u0 = tile + 1; nu = (8 - tile) >> 1; }
                else     { u0 = tile + 2; nu = (7 - tile) >> 1; } }

    // ---- early prefetch (crosses barrier A; vmcnt stays in flight) ----
    HalfT A, B;
    uint4 pd = make_uint4(0, 0, 0, 0), e4k = make_uint4(0, 0, 0, 0);
    ushort_t e512b = 0;
    if (nu > 0) loadh(A, Eb, u0 * 8, str);
    if (!pri) {
      if (nu == 0) loadh(A, Eb, tile * 8, str);
      pd = Eb[(tile * 8 + lo) * str];
      if (dir) e512b = ((const ushort_t*)(Ec + 64 * 512 + myk))[0];
      else if (tile == 0) e4k = Ec[lane * 513 + 512];
    }

    // ---- publish (pri): z, oct max + w2, tile scan + w, tmax ----
    float z = 0.f, pfx = NINF;
    if (pri) {
      z = areg + (dir ? mycs : -mycs);
      zl[myk] = z;
      float gm = fmaxf(z, __shfl_xor(z, 1));
      gm = fmaxf(gm, __shfl_xor(gm, 2));
      gm = fmaxf(gm, __shfl_xor(gm, 4));
      omxl[tile * 8 + lo] = gm;
      wpk2[myk] = f2bf(exp2f((z - gm) * L2E));
      pfx = z;
      float tmax;
      if (!dir) {
        #pragma unroll
        for (int d = 1; d < 64; d <<= 1) {
          float o = __shfl_up(pfx, d);
          if (lane >= d) pfx = fmaxf(pfx, o);
        }
        tmax = __shfl(pfx, 63);
        if (lane == 63) tmxp[tile] = pfx;
      } else {
        #pragma unroll
        for (int d = 1; d < 64; d <<= 1) {
          float o = __shfl_down(pfx, d);
          if (lane < 64 - d) pfx = fmaxf(pfx, o);
        }
        tmax = __shfl(pfx, 0);
        if (lane == 0) tmxp[tile] = pfx;
        if (tid == 0) tmxp[8] = ((s == 0 && myls == 512) ? 0.f : NEG) + mycs512;
      }
      wpk[par][myk] = f2bf(exp2f((z - tmax) * L2E));
    }
    sync_lgkm();                                   // barrier A

    // ---- msh (sec re-derives the scan from zl) ----
    if (!pri) {
      z = zl[myk];
      pfx = z;
      if (!dir) {
        #pragma unroll
        for (int d = 1; d < 64; d <<= 1) {
          float o = __shfl_up(pfx, d);
          if (lane >= d) pfx = fmaxf(pfx, o);
        }
      } else {
        #pragma unroll
        for (int d = 1; d < 64; d <<= 1) {
          float o = __shfl_down(pfx, d);
          if (lane < 64 - d) pfx = fmaxf(pfx, o);
        }
      }
    }
    float msh;
    if (!dir) {
      float off = NINF;
      for (int t2 = 0; t2 < tile; ++t2) off = fmaxf(off, tmxp[t2]);
      float p1 = __shfl_up(pfx, 1);
      msh = fmaxf((lane == 0) ? NINF : p1, off);
    } else {
      float off = tmxp[8];
      for (int t2 = tile + 1; t2 < 8; ++t2) off = fmaxf(off, tmxp[t2]);
      float p1 = __shfl_down(pfx, 1);
      msh = fmaxf((lane == 63) ? NINF : p1, off);
    }

    // ---- consume full units (ping-pong) ----
    float acc = 0.f, s0 = 0.f, s1 = 0.f, s2 = 0.f, s3 = 0.f;
    int u = u0;
    for (int i = 0; i < nu; ++i) {
      loadh(B, Eb, u * 8 + 4, str);
      dotq(A, wq, u * 8, s0, s1, s2, s3);
      if (i + 1 < nu) loadh(A, Eb, (u + 2) * 8, str);
      dotq(B, wq, u * 8 + 4, s0, s1, s2, s3);
      acc += exp2f((tmxp[u] - msh) * L2E) * ((s0 + s1) + (s2 + s3));
      s0 = s1 = s2 = s3 = 0.f;
      u += 2;
    }

    if (!pri) {
      // ---- diag: full octs via oct-scales, partial oct per-element ----
      if (nu > 0) loadh(A, Eb, tile * 8, str);
      loadh(B, Eb, tile * 8 + 4, str);
      acc += diag_octs(A, omx8, wq2t, msh, lo, dir, 0);
      acc += diag_octs(B, omx8, wq2t, msh, lo, dir, 1);
      const float* zp = zl + tile * 64 + (lo << 3);
      #pragma unroll
      for (int r = 0; r < 8; ++r) {
        bool live = dir ? (r > (lane & 7)) : (r < (lane & 7));
        float a = live ? (zp[r] - msh) : NEG;
        uint_t wd = (r < 2) ? pd.x : ((r < 4) ? pd.y : ((r < 6) ? pd.z : pd.w));
        acc += bf2f((ushort_t)(wd >> ((r & 1) * 16))) * exp2f(a * L2E);
      }
      if (dir) acc += bf2f(e512b) * exp2f((tmxp[8] - msh) * L2E);
      psum[myk] = acc;
      // fwd k=512 output column handled by the (otherwise idle) sec tile-0 wave
      if (!dir && tile == 0) {
        float m512 = tmxp[0];
        #pragma unroll
        for (int t2 = 1; t2 < 8; ++t2) m512 = fmaxf(m512, tmxp[t2]);
        uint4 w4 = wq[lane];
        float p = dot2p(e4k.x, w4.x, 0.f);
        p = dot2p(e4k.y, w4.y, p);
        p = dot2p(e4k.z, w4.z, p);
        p = dot2p(e4k.w, w4.w, p);
        p *= exp2f((tmxp[lane >> 3] - m512) * L2E);
        #pragma unroll
        for (int o = 1; o < 64; o <<= 1) p += __shfl_xor(p, o);
        if (lane == 0) {
          float* orow = obuf + (b * (LP_ + 1) + s + 1) * S1_;
          orow[512] = (p > 0.f) ? (mycs512 + m512 + log2f(p) * LN2f) : NEG;
        }
      }
    }
    sync_lgkm();                                   // barrier C

    if (pri) {
      acc += psum[myk];
      float ar;
      if (!dir) ar = (acc > 0.f) ? (mycs + msh + log2f(acc) * LN2f) : NEG;
      else      ar = (acc > 0.f) ? (msh - mycs + log2f(acc) * LN2f) : NEG;
      areg = ar;
      const int row = dir ? (LP_ - 1 - s) : (s + 1);
      float* orow = obuf + (b * (LP_ + 1) + row) * S1_;
      orow[myk] = ar;
      if (dir && tid == 0) orow[512] = NEG;
    }
  }
}

// ---------------- epilogue ----------------
__global__ void k_out(const float* __restrict__ a_buf, const float* __restrict__ b_buf,
                      const int* __restrict__ ls, float* __restrict__ out) {
  const int TOT = B_ * (LP_ + 1) * S1_;
  int idx = blockIdx.x * 256 + threadIdx.x;
  if (idx >= TOT) return;
  int b = idx / ((LP_ + 1) * S1_);
  float M = a_buf[(b * (LP_ + 1) + LP_) * S1_ + ls[b]];
  out[idx] = a_buf[idx] + b_buf[idx] - M;
}

// ---------------- launcher ----------------
extern "C" void kernel_launch(void* const* d_in, const int* in_sizes, int n_in,
                              void* d_out, int out_size, void* d_ws, size_t ws_size,
                              hipStream_t stream) {
  const float* ss3     = (const float*)d_in[0];
  const float* Q       = (const float*)d_in[1];
  const int*   pattern = (const int*)d_in[2];
  const int*   ls      = (const int*)d_in[3];
  float* out = (float*)d_out;

  float* ws    = (float*)d_ws;
  float* cs    = ws;                                    // B*3*S1 floats
  float* a_buf = cs + B_ * 3 * S1_;                     // B*17*S1
  float* b_buf = a_buf + B_ * (LP_ + 1) * S1_;
  uint4* Efo = (uint4*)(b_buf + B_ * (LP_ + 1) * S1_);  // 3*64*513 uint4
  uint4* Ebo = Efo + 3 * 64 * 513;                      // 3*65*512 uint4

  k_cumsum<<<dim3(B_, 3), 512, 0, stream>>>(ss3, cs);
  k_prep  <<<dim3(9, 8, 3), dim3(64, 8), 0, stream>>>(Q, Efo, Ebo);
  k_scan  <<<2 * B_, 1024, 0, stream>>>(Efo, Ebo, cs, pattern, ls, a_buf, b_buf);

  const int TOT = B_ * (LP_ + 1) * S1_;
  k_out<<<(TOT + 255) / 256, 256, 0, stream>>>(a_buf, b_buf, ls, out);
}